// Round 10
// baseline (37.489 us; speedup 1.0000x reference)
//
#include <hip/hip_runtime.h>
#include <math.h>

// out[b,o] = min_i(W[o,i]+X[b,i]) + max_i(W[o,i]+X[b,i])
// B=1024, OUT=1024, IN=512, fp32.
//
// R10: split operands across pipes so the main loop is PURE VALU.
//  - lane = b. X k-slice (64 floats) loaded ONCE into VGPRs (xq[16] f4).
//  - W[o,k] is wave-uniform -> readfirstlane'd base => compiler emits
//    s_load into SGPRs; v_add_f32 consumes the SGPR operand directly.
//  - main loop: no LDS, no VMEM, no barriers. 2 VALU/triple + asm min3/max3.
//  - block = 512 thr = 8 waves = 8 k-splits of 64; tile 64b x 16o;
//    grid (1024/16, 1024/64) = 1024 blocks. ~115 VGPR -> 4 waves/SIMD
//    (covers s_load latency with TLP).
//  - 3-round LDS merge tree at the end only (8 KB/wave dump, 32 KB total).

typedef float f4 __attribute__((ext_vector_type(4)));

constexpr int B_DIM  = 1024;
constexpr int O_DIM  = 1024;
constexpr int IN_DIM = 512;

constexpr int NB = 64;   // b per block
constexpr int NO = 16;   // o per block
constexpr int KW = 64;   // k per wave (512 / 8 waves)

__global__ __launch_bounds__(512) void tropical_gemm(
    const float* __restrict__ X, const float* __restrict__ W,
    float* __restrict__ out) {
    __shared__ float lds[8192];    // 32 KB, merge tree only

    const int tid  = threadIdx.x;
    const int w    = tid >> 6;
    const int lane = tid & 63;
    const int b0   = blockIdx.y * NB;
    const int o0   = blockIdx.x * NO;
    // force wave-uniformity so W addresses go through SMEM/SGPR
    const int wu   = __builtin_amdgcn_readfirstlane(w);

    // ---- X k-slice into VGPRs (once; per-lane row => uncoalesced but tiny:
    // 256 distinct lines per wave, L2-resident after first pass) ----
    f4 xq[16];
    {
        const float* xp = X + (size_t)(b0 + lane) * IN_DIM + wu * KW;
#pragma unroll
        for (int j = 0; j < 16; ++j) xq[j] = *(const f4*)(xp + 4 * j);
    }

    const float* wbase = W + (size_t)o0 * IN_DIM + wu * KW;  // uniform

    float mn[NO], mx[NO];
#pragma unroll
    for (int o = 0; o < NO; ++o) { mn[o] = INFINITY; mx[o] = -INFINITY; }

    // ---- pure-VALU main loop: fully unrolled 16 o x 64 k ----
#pragma unroll
    for (int o = 0; o < NO; ++o) {
        const float* wr = wbase + (size_t)o * IN_DIM;   // uniform row
#pragma unroll
        for (int k = 0; k < KW; k += 2) {
            float s0 = xq[k >> 2][k & 3] + wr[k];          // v_add v,s,v
            float s1 = xq[(k + 1) >> 2][(k + 1) & 3] + wr[k + 1];
            asm("v_min3_f32 %0, %1, %2, %0"
                : "+v"(mn[o]) : "v"(s0), "v"(s1));
            asm("v_max3_f32 %0, %1, %2, %0"
                : "+v"(mx[o]) : "v"(s0), "v"(s1));
        }
    }

    // ---- merge 8 wave partials: 3-round LDS tree ----
    // per-lane state = 32 floats; slot = 2048 floats (8 KB), 4 slots = 32 KB
#define DUMP_STATE(slot)                                                      \
    do {                                                                      \
        float* p_ = lds + (slot) * 2048 + lane * 4;                           \
        _Pragma("unroll")                                                     \
        for (int c_ = 0; c_ < 4; ++c_) {                                      \
            f4 vn_ = {mn[4 * c_], mn[4 * c_ + 1], mn[4 * c_ + 2], mn[4 * c_ + 3]}; \
            f4 vx_ = {mx[4 * c_], mx[4 * c_ + 1], mx[4 * c_ + 2], mx[4 * c_ + 3]}; \
            *(f4*)(p_ + c_ * 256)       = vn_;                                \
            *(f4*)(p_ + (4 + c_) * 256) = vx_;                                \
        }                                                                     \
    } while (0)

#define MERGE_STATE(slot)                                                     \
    do {                                                                      \
        const float* p_ = lds + (slot) * 2048 + lane * 4;                     \
        _Pragma("unroll")                                                     \
        for (int c_ = 0; c_ < 4; ++c_) {                                      \
            f4 vn_ = *(const f4*)(p_ + c_ * 256);                             \
            f4 vx_ = *(const f4*)(p_ + (4 + c_) * 256);                       \
            mn[4 * c_]     = fminf(mn[4 * c_],     vn_[0]);                   \
            mn[4 * c_ + 1] = fminf(mn[4 * c_ + 1], vn_[1]);                   \
            mn[4 * c_ + 2] = fminf(mn[4 * c_ + 2], vn_[2]);                   \
            mn[4 * c_ + 3] = fminf(mn[4 * c_ + 3], vn_[3]);                   \
            mx[4 * c_]     = fmaxf(mx[4 * c_],     vx_[0]);                   \
            mx[4 * c_ + 1] = fmaxf(mx[4 * c_ + 1], vx_[1]);                   \
            mx[4 * c_ + 2] = fmaxf(mx[4 * c_ + 2], vx_[2]);                   \
            mx[4 * c_ + 3] = fmaxf(mx[4 * c_ + 3], vx_[3]);                   \
        }                                                                     \
    } while (0)

    __syncthreads();
    // Round 1: 8 -> 4
    if (w >= 4) DUMP_STATE(w - 4);
    __syncthreads();
    if (w < 4) MERGE_STATE(w);
    __syncthreads();
    // Round 2: 4 -> 2
    if (w == 2) DUMP_STATE(0);
    if (w == 3) DUMP_STATE(1);
    __syncthreads();
    if (w == 0) MERGE_STATE(0);
    if (w == 1) MERGE_STATE(1);
    __syncthreads();
    // Round 3: 2 -> 1
    if (w == 1) DUMP_STATE(0);
    __syncthreads();
    if (w == 0) {
        MERGE_STATE(0);
        // lane writes out[b0+lane][o0 .. o0+16) = one 64B line
        float* op = out + (size_t)(b0 + lane) * O_DIM + o0;
#pragma unroll
        for (int c = 0; c < 4; ++c) {
            f4 v = {mn[4 * c]     + mx[4 * c],
                    mn[4 * c + 1] + mx[4 * c + 1],
                    mn[4 * c + 2] + mx[4 * c + 2],
                    mn[4 * c + 3] + mx[4 * c + 3]};
            *(f4*)(op + 4 * c) = v;
        }
    }
#undef DUMP_STATE
#undef MERGE_STATE
}

extern "C" void kernel_launch(void* const* d_in, const int* in_sizes, int n_in,
                              void* d_out, int out_size, void* d_ws, size_t ws_size,
                              hipStream_t stream) {
    (void)in_sizes; (void)n_in; (void)d_ws; (void)ws_size; (void)out_size;
    const float* X = (const float*)d_in[0];
    const float* W = (const float*)d_in[1];
    float* out     = (float*)d_out;

    dim3 grid(O_DIM / NO, B_DIM / NB);   // (64, 16) = 1024 blocks
    tropical_gemm<<<grid, dim3(512), 0, stream>>>(X, W, out);
}

// Round 11
// 35.753 us; speedup vs baseline: 1.0486x; 1.0486x over previous
//
#include <hip/hip_runtime.h>
#include <math.h>

// out[b,o] = min_i(W[o,i]+X[b,i]) + max_i(W[o,i]+X[b,i])
// B=1024, OUT=1024, IN=512, fp32.
//
// R11: broadcast-W structure. lane=b. X k-slice in VGPRs (xq[16] f4,
// loaded once via coalesced LDS transpose bounce). W staged in LDS once;
// main loop reads W quads via SAME-ADDRESS ds_read_b128 = hardware
// broadcast: 1 LDS instr per 256 triples (~30x fewer LDS instrs than the
// R6 gather scheme), compile-time offsets, no barriers, no VMEM.
// Block 512thr/8 waves (k-split x8, KW=64), grid (64,16)=1024 blocks =
// 2 blocks/CU = 4 waves/SIMD. 3-round merge tree overlays the W region.

typedef float f4 __attribute__((ext_vector_type(4)));

constexpr int B_DIM  = 1024;
constexpr int O_DIM  = 1024;
constexpr int IN_DIM = 512;

constexpr int NB = 64;    // b per block (= lanes)
constexpr int NO = 16;    // o per block
constexpr int KW = 64;    // k per wave

// LDS floats: X chunk 64 rows x 68 (pad 4 -> 8-way granule spread, 16B
// aligned) = 4352; W 16 o x 512 k = 8192. Merge overlays W (4 x 2048).
constexpr int XREG     = 64 * 68;   // 4352 floats
constexpr int WREG_OFF = XREG;

__global__ __launch_bounds__(512, 4) void tropical_gemm(
    const float* __restrict__ X, const float* __restrict__ W,
    float* __restrict__ out) {
    __shared__ float lds[XREG + 16 * 512];   // 12544 floats = 50176 B

    const int tid  = threadIdx.x;
    const int w    = tid >> 6;     // wave 0..7 (k-slice owner)
    const int lane = tid & 63;     // = local b
    const int b0   = blockIdx.y * NB;
    const int o0   = blockIdx.x * NO;

    // ---- stage W[16 o][512 k] into LDS (coalesced, 4 quads/thread) ----
    {
        const int o   = tid >> 5;        // 0..15
        const int kq0 = tid & 31;        // 0..31
        const float* wp = W + (size_t)(o0 + o) * IN_DIM;
        float* dst = lds + WREG_OFF + o * 512;
#pragma unroll
        for (int p = 0; p < 4; ++p) {
            const int kq = kq0 + p * 32;
            *(f4*)(dst + kq * 4) = *(const f4*)(wp + kq * 4);
        }
    }

    // ---- X: 8 chunks of 64 k bounce through LDS; wave c keeps chunk c ----
    f4 xq[16];   // this wave's 64-k slice, 16 quads
    {
        const int r  = tid >> 3;         // 0..63 (row)
        const int q0 = tid & 7;          // 0..7  (quad pair base)
        const float* xrow = X + (size_t)(b0 + r) * IN_DIM;
        f4 ga = *(const f4*)(xrow + q0 * 4);
        f4 gb = *(const f4*)(xrow + (q0 + 8) * 4);
        for (int c = 0; c < 8; ++c) {
            *(f4*)(lds + r * 68 + q0 * 4)       = ga;
            *(f4*)(lds + r * 68 + (q0 + 8) * 4) = gb;
            __syncthreads();
            if (c < 7) {   // prefetch next chunk's globals
                ga = *(const f4*)(xrow + (c + 1) * 64 + q0 * 4);
                gb = *(const f4*)(xrow + (c + 1) * 64 + (q0 + 8) * 4);
            }
            if (w == c) {
#pragma unroll
                for (int j = 0; j < 16; ++j)
                    xq[j] = *(const f4*)(lds + lane * 68 + j * 4);
            }
            __syncthreads();
        }
    }

    float mn[NO], mx[NO];
#pragma unroll
    for (int o = 0; o < NO; ++o) { mn[o] = INFINITY; mx[o] = -INFINITY; }

    // ---- main loop: 256 quads (16 o x 16 kq), broadcast ds_read + VALU ----
    // quad Q: o = Q>>4, kq = Q&15. Byte offset is compile-time constant.
    const char* wb = (const char*)(lds + WREG_OFF) + w * 256;  // + w's k-slice

#define LOADW(P, Q)                                                           \
    P = *(const f4*)(wb + ((Q) >> 4) * 2048 + ((Q) & 15) * 16)

#define CMPQ(P, Q)                                                            \
    do {                                                                      \
        float s0_ = xq[(Q) & 15][0] + P[0];                                   \
        float s1_ = xq[(Q) & 15][1] + P[1];                                   \
        float s2_ = xq[(Q) & 15][2] + P[2];                                   \
        float s3_ = xq[(Q) & 15][3] + P[3];                                   \
        asm("v_min3_f32 %0, %1, %2, %0"                                       \
            : "+v"(mn[(Q) >> 4]) : "v"(s0_), "v"(s1_));                       \
        asm("v_max3_f32 %0, %1, %2, %0"                                       \
            : "+v"(mx[(Q) >> 4]) : "v"(s0_), "v"(s1_));                       \
        asm("v_min3_f32 %0, %1, %2, %0"                                       \
            : "+v"(mn[(Q) >> 4]) : "v"(s2_), "v"(s3_));                       \
        asm("v_max3_f32 %0, %1, %2, %0"                                       \
            : "+v"(mx[(Q) >> 4]) : "v"(s2_), "v"(s3_));                       \
    } while (0)

    {
        f4 wA, wB, wC, wD;       // 4-deep rotating prefetch
        LOADW(wA, 0); LOADW(wB, 1); LOADW(wC, 2); LOADW(wD, 3);
#pragma unroll
        for (int qp = 0; qp < 63; ++qp) {
            CMPQ(wA, 4 * qp);     LOADW(wA, 4 * qp + 4);
            CMPQ(wB, 4 * qp + 1); LOADW(wB, 4 * qp + 5);
            CMPQ(wC, 4 * qp + 2); LOADW(wC, 4 * qp + 6);
            CMPQ(wD, 4 * qp + 3); LOADW(wD, 4 * qp + 7);
        }
        CMPQ(wA, 252); CMPQ(wB, 253); CMPQ(wC, 254); CMPQ(wD, 255);
    }
#undef LOADW
#undef CMPQ

    // ---- merge 8 k-split partials: 3-round LDS tree (overlay W region) ----
    // per-lane state = 32 floats; slot = 2048 floats (8 KB), 4 slots.
#define DUMP_STATE(slot)                                                      \
    do {                                                                      \
        float* p_ = lds + WREG_OFF + (slot) * 2048 + lane * 4;                \
        _Pragma("unroll")                                                     \
        for (int c_ = 0; c_ < 4; ++c_) {                                      \
            f4 vn_ = {mn[4 * c_], mn[4 * c_ + 1], mn[4 * c_ + 2], mn[4 * c_ + 3]}; \
            f4 vx_ = {mx[4 * c_], mx[4 * c_ + 1], mx[4 * c_ + 2], mx[4 * c_ + 3]}; \
            *(f4*)(p_ + c_ * 256)       = vn_;                                \
            *(f4*)(p_ + (4 + c_) * 256) = vx_;                                \
        }                                                                     \
    } while (0)

#define MERGE_STATE(slot)                                                     \
    do {                                                                      \
        const float* p_ = lds + WREG_OFF + (slot) * 2048 + lane * 4;          \
        _Pragma("unroll")                                                     \
        for (int c_ = 0; c_ < 4; ++c_) {                                      \
            f4 vn_ = *(const f4*)(p_ + c_ * 256);                             \
            f4 vx_ = *(const f4*)(p_ + (4 + c_) * 256);                       \
            mn[4 * c_]     = fminf(mn[4 * c_],     vn_[0]);                   \
            mn[4 * c_ + 1] = fminf(mn[4 * c_ + 1], vn_[1]);                   \
            mn[4 * c_ + 2] = fminf(mn[4 * c_ + 2], vn_[2]);                   \
            mn[4 * c_ + 3] = fminf(mn[4 * c_ + 3], vn_[3]);                   \
            mx[4 * c_]     = fmaxf(mx[4 * c_],     vx_[0]);                   \
            mx[4 * c_ + 1] = fmaxf(mx[4 * c_ + 1], vx_[1]);                   \
            mx[4 * c_ + 2] = fmaxf(mx[4 * c_ + 2], vx_[2]);                   \
            mx[4 * c_ + 3] = fmaxf(mx[4 * c_ + 3], vx_[3]);                   \
        }                                                                     \
    } while (0)

    __syncthreads();                 // all waves done reading W region
    // Round 1: 8 -> 4
    if (w >= 4) DUMP_STATE(w - 4);
    __syncthreads();
    if (w < 4) MERGE_STATE(w);
    __syncthreads();
    // Round 2: 4 -> 2
    if (w == 2) DUMP_STATE(0);
    if (w == 3) DUMP_STATE(1);
    __syncthreads();
    if (w == 0) MERGE_STATE(0);
    if (w == 1) MERGE_STATE(1);
    __syncthreads();
    // Round 3: 2 -> 1
    if (w == 1) DUMP_STATE(0);
    __syncthreads();
    if (w == 0) {
        MERGE_STATE(0);
        float* op = out + (size_t)(b0 + lane) * O_DIM + o0;
#pragma unroll
        for (int c = 0; c < 4; ++c) {
            f4 v = {mn[4 * c]     + mx[4 * c],
                    mn[4 * c + 1] + mx[4 * c + 1],
                    mn[4 * c + 2] + mx[4 * c + 2],
                    mn[4 * c + 3] + mx[4 * c + 3]};
            *(f4*)(op + 4 * c) = v;
        }
    }
#undef DUMP_STATE
#undef MERGE_STATE
}

extern "C" void kernel_launch(void* const* d_in, const int* in_sizes, int n_in,
                              void* d_out, int out_size, void* d_ws, size_t ws_size,
                              hipStream_t stream) {
    (void)in_sizes; (void)n_in; (void)d_ws; (void)ws_size; (void)out_size;
    const float* X = (const float*)d_in[0];
    const float* W = (const float*)d_in[1];
    float* out     = (float*)d_out;

    dim3 grid(O_DIM / NO, B_DIM / NB);   // (64, 16) = 1024 blocks
    tropical_gemm<<<grid, dim3(512), 0, stream>>>(X, W, out);
}

// Round 12
// 32.521 us; speedup vs baseline: 1.1527x; 1.0994x over previous
//
#include <hip/hip_runtime.h>
#include <math.h>

// out[b,o] = min_i(W[o,i]+X[b,i]) + max_i(W[o,i]+X[b,i])
// B=1024, OUT=1024, IN=512, fp32.
//
// R12 = R6 (best: 31.7us) + FULL-STAGE register prefetch.
// R6 post-mortem: wall == LDS-pipe time + VALU time, fully serialized --
// the 1-kpair-ahead pipeline couldn't cover LDS queueing delay at ~80%
// pipe utilization. Fix: load all 4 k-pairs' fragments (24 ds_read_b128,
// 96 VGPRs) at stage top; compiler's partial lgkmcnt waits let kp1-3's
// latency hide under kp0-2's 128-VALU bursts, overlapping the per-CU LDS
// pipe with the per-SIMD VALU across the 8 resident waves.
// Tile 64x32, 256thr/4 waves, wave-private k-slice 128, dbuf LDS 6KB/wave,
// zero main-loop barriers, asm v_min3/v_max3, 2-round macro merge tree.
// Grid 512 blocks = 2 blocks/CU (VGPR ~195 -> 10 waves/CU cap, OK).

typedef float f4 __attribute__((ext_vector_type(4)));

constexpr int B_DIM  = 1024;
constexpr int O_DIM  = 1024;
constexpr int IN_DIM = 512;

constexpr int TM     = 64;           // batch-tile
constexpr int TN     = 32;           // out-tile
constexpr int KW     = 128;          // k per wave (512 / 4 waves)
constexpr int BK     = 8;            // k per stage (4 k-pairs)
constexpr int NSTAGE = KW / BK;      // 16

__global__ __launch_bounds__(256) void tropical_gemm(
    const float* __restrict__ X, const float* __restrict__ W,
    float* __restrict__ out) {
    __shared__ float lds[8192];   // 32 KB: loop 4x1536, merge 2x4096 overlay

    const int tid  = threadIdx.x;
    const int w    = tid >> 6;     // wave 0..3
    const int lane = tid & 63;
    const int im   = lane >> 3;    // micro-row block 0..7 (8 X rows)
    const int in_  = lane & 7;     // micro-col block 0..7 (4 W cols)
    const int b0   = blockIdx.y * TM;
    const int o0   = blockIdx.x * TN;
    const int xoff = im * 8;
    const int woff = in_ * 4;
    const int wrow = lane >> 1;            // W staging: 2 lanes per row
    const int wk4  = (lane & 1) * 4;       // which k-half of the row's 8

    const float* Xp = X + (size_t)(b0 + lane) * IN_DIM + w * KW;
    const float* Wp = W + (size_t)(o0 + wrow) * IN_DIM + w * KW + wk4;

    float* wbase = &lds[w * 1536];  // wave-private: [buf2][X 8x64 | W 8x32]

    float mn[8][4], mx[8][4];
#pragma unroll
    for (int i = 0; i < 8; ++i)
#pragma unroll
        for (int j = 0; j < 4; ++j) { mn[i][j] = INFINITY; mx[i][j] = -INFINITY; }

    // stage one 8k chunk: X k-major [k][64], W k-major [k][32]
#define STAGE(bufsel)                                                         \
    do {                                                                      \
        float* d_ = wbase + (bufsel) * 768;                                   \
        _Pragma("unroll")                                                     \
        for (int j_ = 0; j_ < 4; ++j_) {                                      \
            d_[j_ * 64 + lane]       = xa[j_];                                \
            d_[(4 + j_) * 64 + lane] = xb[j_];                                \
            d_[512 + (wk4 + j_) * 32 + wrow] = wv[j_];                        \
        }                                                                     \
    } while (0)

    // load one k-pair's fragments into named register set P
#define LOADQ(P, kp)                                                          \
    do {                                                                      \
        P##x0  = *(const f4*)(sXf + (2 * (kp)) * 64 + xoff);                  \
        P##x0b = *(const f4*)(sXf + (2 * (kp)) * 64 + xoff + 4);              \
        P##x1  = *(const f4*)(sXf + (2 * (kp) + 1) * 64 + xoff);              \
        P##x1b = *(const f4*)(sXf + (2 * (kp) + 1) * 64 + xoff + 4);          \
        P##w0  = *(const f4*)(sWf + (2 * (kp)) * 32 + woff);                  \
        P##w1  = *(const f4*)(sWf + (2 * (kp) + 1) * 32 + woff);              \
    } while (0)

    // 32 (a,b) pairs over 2 k's: 2 v_add + v_min3 + v_max3 each
#define COMPUTE(P)                                                            \
    do {                                                                      \
        _Pragma("unroll")                                                     \
        for (int a_ = 0; a_ < 8; ++a_) {                                      \
            const float x0_ = (a_ < 4) ? P##x0[a_] : P##x0b[a_ - 4];          \
            const float x1_ = (a_ < 4) ? P##x1[a_] : P##x1b[a_ - 4];          \
            _Pragma("unroll")                                                 \
            for (int b_ = 0; b_ < 4; ++b_) {                                  \
                float s0_ = x0_ + P##w0[b_];                                  \
                float s1_ = x1_ + P##w1[b_];                                  \
                asm("v_min3_f32 %0, %1, %2, %0"                               \
                    : "+v"(mn[a_][b_]) : "v"(s0_), "v"(s1_));                 \
                asm("v_max3_f32 %0, %1, %2, %0"                               \
                    : "+v"(mx[a_][b_]) : "v"(s0_), "v"(s1_));                 \
            }                                                                 \
        }                                                                     \
    } while (0)

    // ---- prologue ----
    f4 xa = *(const f4*)(Xp);
    f4 xb = *(const f4*)(Xp + 4);
    f4 wv = *(const f4*)(Wp);
    STAGE(0);

#pragma unroll 1
    for (int s = 0; s < NSTAGE; ++s) {
        if (s + 1 < NSTAGE) {  // prefetch next chunk's globals (HBM/L2 latency
            xa = *(const f4*)(Xp + (s + 1) * BK);   // hides under this stage)
            xb = *(const f4*)(Xp + (s + 1) * BK + 4);
            wv = *(const f4*)(Wp + (s + 1) * BK);
        }

        const float* sXf = wbase + (s & 1) * 768;
        const float* sWf = sXf + 512;

        // full-stage fragment prefetch: 24 ds_read_b128 issued up front
        f4 P0x0, P0x0b, P0x1, P0x1b, P0w0, P0w1;
        f4 P1x0, P1x0b, P1x1, P1x1b, P1w0, P1w1;
        f4 P2x0, P2x0b, P2x1, P2x1b, P2w0, P2w1;
        f4 P3x0, P3x0b, P3x1, P3x1b, P3w0, P3w1;
        LOADQ(P0, 0);
        LOADQ(P1, 1);
        LOADQ(P2, 2);
        LOADQ(P3, 3);

        COMPUTE(P0);
        COMPUTE(P1);
        COMPUTE(P2);
        COMPUTE(P3);

        if (s + 1 < NSTAGE) STAGE((s + 1) & 1);
    }
#undef STAGE
#undef LOADQ
#undef COMPUTE

    // ---- merge 4 wave partials: 2-round LDS tree ----
    // state/lane = 16 quads: q=r -> mn[r][0..3], q=8+r -> mx[r][0..3]
#define DUMP_STATE(slotbase)                                                  \
    do {                                                                      \
        float* p_ = (slotbase) + lane * 4;                                    \
        _Pragma("unroll")                                                     \
        for (int r_ = 0; r_ < 8; ++r_) {                                      \
            *(float4*)(p_ + r_ * 256) =                                       \
                make_float4(mn[r_][0], mn[r_][1], mn[r_][2], mn[r_][3]);      \
            *(float4*)(p_ + (8 + r_) * 256) =                                 \
                make_float4(mx[r_][0], mx[r_][1], mx[r_][2], mx[r_][3]);      \
        }                                                                     \
    } while (0)

#define MERGE_STATE(slotbase)                                                 \
    do {                                                                      \
        const float* p_ = (slotbase) + lane * 4;                              \
        _Pragma("unroll")                                                     \
        for (int r_ = 0; r_ < 8; ++r_) {                                      \
            float4 vn_ = *(const float4*)(p_ + r_ * 256);                     \
            float4 vx_ = *(const float4*)(p_ + (8 + r_) * 256);               \
            mn[r_][0] = fminf(mn[r_][0], vn_.x);                              \
            mn[r_][1] = fminf(mn[r_][1], vn_.y);                              \
            mn[r_][2] = fminf(mn[r_][2], vn_.z);                              \
            mn[r_][3] = fminf(mn[r_][3], vn_.w);                              \
            mx[r_][0] = fmaxf(mx[r_][0], vx_.x);                              \
            mx[r_][1] = fmaxf(mx[r_][1], vx_.y);                              \
            mx[r_][2] = fmaxf(mx[r_][2], vx_.z);                              \
            mx[r_][3] = fmaxf(mx[r_][3], vx_.w);                              \
        }                                                                     \
    } while (0)

    float* slotA = lds;           // 4096 floats
    float* slotB = lds + 4096;

    __syncthreads();
    if (w == 2) DUMP_STATE(slotA);
    if (w == 3) DUMP_STATE(slotB);
    __syncthreads();
    if (w == 0) MERGE_STATE(slotA);   // w0 <- {w0,w2}
    if (w == 1) MERGE_STATE(slotB);   // w1 <- {w1,w3}
    __syncthreads();
    if (w == 1) DUMP_STATE(slotA);
    __syncthreads();
    if (w == 0) {
        MERGE_STATE(slotA);           // w0 <- all
        float* op = out + (size_t)(b0 + im * 8) * O_DIM + o0 + in_ * 4;
#pragma unroll
        for (int r = 0; r < 8; ++r)
            *(float4*)(op + (size_t)r * O_DIM) =
                make_float4(mn[r][0] + mx[r][0], mn[r][1] + mx[r][1],
                            mn[r][2] + mx[r][2], mn[r][3] + mx[r][3]);
    }
#undef DUMP_STATE
#undef MERGE_STATE
}

extern "C" void kernel_launch(void* const* d_in, const int* in_sizes, int n_in,
                              void* d_out, int out_size, void* d_ws, size_t ws_size,
                              hipStream_t stream) {
    (void)in_sizes; (void)n_in; (void)d_ws; (void)ws_size; (void)out_size;
    const float* X = (const float*)d_in[0];
    const float* W = (const float*)d_in[1];
    float* out     = (float*)d_out;

    dim3 grid(O_DIM / TN, B_DIM / TM);  // (32, 16) = 512 blocks = 2/CU
    tropical_gemm<<<grid, dim3(256), 0, stream>>>(X, W, out);
}

// Round 13
// 31.018 us; speedup vs baseline: 1.2086x; 1.0485x over previous
//
#include <hip/hip_runtime.h>
#include <math.h>

// out[b,o] = min_i(W[o,i]+X[b,i]) + max_i(W[o,i]+X[b,i])
// B=1024, OUT=1024, IN=512, fp32.
//
// R13 = R6 (best: 31.7us) + cross-stage 2-deep rotating LDS pipeline.
// R6/R12 post-mortem: stage-boundary drains leave COMPUTE waiting on reads
// issued only ~256cyc earlier vs ~550cyc loaded-queue latency -> LDS pipe
// ~50% utilized, wall ~= LDS+VALU serialized. Fix: 4 register sets (kp mod
// 4); at each kp slot issue LOADQ(kp+2) then COMPUTE(kp) -> every wait has
// >=512cyc cover, pipeline never drains (STAGE's ds_writes precede next-
// buffer LOADQs in program order; same-wave DS ops are in-order so the
// LDS RAW is safe without barriers).
// Tile 64x32, 256thr/4 waves, wave-private k-slice 128, dbuf 6KB/wave,
// zero main-loop barriers, asm v_min3/v_max3, 2-round macro merge tree.
// Grid 512 blocks = 2 blocks/CU, 8 waves/CU. LDS-pipe floor ~19us.

typedef float f4 __attribute__((ext_vector_type(4)));

constexpr int B_DIM  = 1024;
constexpr int O_DIM  = 1024;
constexpr int IN_DIM = 512;

constexpr int TM     = 64;           // batch-tile
constexpr int TN     = 32;           // out-tile
constexpr int KW     = 128;          // k per wave (512 / 4 waves)
constexpr int BK     = 8;            // k per stage (4 k-pairs)
constexpr int NSTAGE = KW / BK;      // 16

__global__ __launch_bounds__(256) void tropical_gemm(
    const float* __restrict__ X, const float* __restrict__ W,
    float* __restrict__ out) {
    __shared__ float lds[8192];   // 32 KB: loop 4x1536, merge 2x4096 overlay

    const int tid  = threadIdx.x;
    const int w    = tid >> 6;     // wave 0..3
    const int lane = tid & 63;
    const int im   = lane >> 3;    // micro-row block 0..7 (8 X rows)
    const int in_  = lane & 7;     // micro-col block 0..7 (4 W cols)
    const int b0   = blockIdx.y * TM;
    const int o0   = blockIdx.x * TN;
    const int xoff = im * 8;
    const int woff = in_ * 4;
    const int wrow = lane >> 1;            // W staging: 2 lanes per row
    const int wk4  = (lane & 1) * 4;       // which k-half of the row's 8

    const float* Xp = X + (size_t)(b0 + lane) * IN_DIM + w * KW;
    const float* Wp = W + (size_t)(o0 + wrow) * IN_DIM + w * KW + wk4;

    float* wbase = &lds[w * 1536];  // wave-private: [buf2][X 8x64 | W 8x32]

    float mn[8][4], mx[8][4];
#pragma unroll
    for (int i = 0; i < 8; ++i)
#pragma unroll
        for (int j = 0; j < 4; ++j) { mn[i][j] = INFINITY; mx[i][j] = -INFINITY; }

    // stage one 8k chunk from global-prefetch set G: X k-major [k][64], W [k][32]
#define STAGE(bufsel, G)                                                      \
    do {                                                                      \
        float* d_ = wbase + (bufsel) * 768;                                   \
        _Pragma("unroll")                                                     \
        for (int j_ = 0; j_ < 4; ++j_) {                                      \
            d_[j_ * 64 + lane]       = xa##G[j_];                             \
            d_[(4 + j_) * 64 + lane] = xb##G[j_];                             \
            d_[512 + (wk4 + j_) * 32 + wrow] = wv##G[j_];                     \
        }                                                                     \
    } while (0)

#define PREFETCH(G, stg)                                                      \
    do {                                                                      \
        xa##G = *(const f4*)(Xp + (stg) * BK);                                \
        xb##G = *(const f4*)(Xp + (stg) * BK + 4);                            \
        wv##G = *(const f4*)(Wp + (stg) * BK);                                \
    } while (0)

    // load one k-pair's fragments (kp 0..3 within buffer) into set P
#define LOADQ(P, cX, cW, kp)                                                  \
    do {                                                                      \
        P##x0  = *(const f4*)((cX) + (2 * (kp)) * 64 + xoff);                 \
        P##x0b = *(const f4*)((cX) + (2 * (kp)) * 64 + xoff + 4);             \
        P##x1  = *(const f4*)((cX) + (2 * (kp) + 1) * 64 + xoff);             \
        P##x1b = *(const f4*)((cX) + (2 * (kp) + 1) * 64 + xoff + 4);         \
        P##w0  = *(const f4*)((cW) + (2 * (kp)) * 32 + woff);                 \
        P##w1  = *(const f4*)((cW) + (2 * (kp) + 1) * 32 + woff);             \
    } while (0)

    // 32 (a,b) pairs over 2 k's: 2 v_add + v_min3 + v_max3 each
#define COMPUTE(P)                                                            \
    do {                                                                      \
        _Pragma("unroll")                                                     \
        for (int a_ = 0; a_ < 8; ++a_) {                                      \
            const float x0_ = (a_ < 4) ? P##x0[a_] : P##x0b[a_ - 4];          \
            const float x1_ = (a_ < 4) ? P##x1[a_] : P##x1b[a_ - 4];          \
            _Pragma("unroll")                                                 \
            for (int b_ = 0; b_ < 4; ++b_) {                                  \
                float s0_ = x0_ + P##w0[b_];                                  \
                float s1_ = x1_ + P##w1[b_];                                  \
                asm("v_min3_f32 %0, %1, %2, %0"                               \
                    : "+v"(mn[a_][b_]) : "v"(s0_), "v"(s1_));                 \
                asm("v_max3_f32 %0, %1, %2, %0"                               \
                    : "+v"(mx[a_][b_]) : "v"(s0_), "v"(s1_));                 \
            }                                                                 \
        }                                                                     \
    } while (0)

    // rotating register sets (persist across stages)
    f4 Ax0, Ax0b, Ax1, Ax1b, Aw0, Aw1;
    f4 Bx0, Bx0b, Bx1, Bx1b, Bw0, Bw1;
    f4 Cx0, Cx0b, Cx1, Cx1b, Cw0, Cw1;
    f4 Dx0, Dx0b, Dx1, Dx1b, Dw0, Dw1;
    f4 xa0, xb0, wv0, xa1, xb1, wv1;

    const float* bX0 = wbase;         // buffer 0
    const float* bW0 = bX0 + 512;
    const float* bX1 = wbase + 768;   // buffer 1
    const float* bW1 = bX1 + 512;

    // ---- prologue ----
    PREFETCH(0, 0);
    STAGE(0, 0);
    PREFETCH(1, 1);
    LOADQ(A, bX0, bW0, 0);
    LOADQ(B, bX0, bW0, 1);

#pragma unroll 1
    for (int s2 = 0; s2 < 8; ++s2) {
        // ---- even stage s = 2*s2 (cur buf0, next buf1, next g = g1) ----
        LOADQ(C, bX0, bW0, 2);  COMPUTE(A);
        LOADQ(D, bX0, bW0, 3);  COMPUTE(B);
        STAGE(1, 1);                          // stage s+1 (always exists)
        if (s2 < 7) PREFETCH(0, 2 * s2 + 2);  // g0 <- globals for stage s+2
        LOADQ(A, bX1, bW1, 0);  COMPUTE(C);
        LOADQ(B, bX1, bW1, 1);  COMPUTE(D);

        // ---- odd stage s = 2*s2+1 (cur buf1, next buf0, next g = g0) ----
        LOADQ(C, bX1, bW1, 2);  COMPUTE(A);
        LOADQ(D, bX1, bW1, 3);  COMPUTE(B);
        if (s2 < 7) {
            STAGE(0, 0);                      // stage s+1
            PREFETCH(1, 2 * s2 + 3);          // g1 <- globals for stage s+2
            LOADQ(A, bX0, bW0, 0);
        }
        COMPUTE(C);
        if (s2 < 7) LOADQ(B, bX0, bW0, 1);
        COMPUTE(D);
    }
#undef STAGE
#undef PREFETCH
#undef LOADQ
#undef COMPUTE

    // ---- merge 4 wave partials: 2-round LDS tree ----
    // state/lane = 16 quads: q=r -> mn[r][0..3], q=8+r -> mx[r][0..3]
#define DUMP_STATE(slotbase)                                                  \
    do {                                                                      \
        float* p_ = (slotbase) + lane * 4;                                    \
        _Pragma("unroll")                                                     \
        for (int r_ = 0; r_ < 8; ++r_) {                                      \
            *(float4*)(p_ + r_ * 256) =                                       \
                make_float4(mn[r_][0], mn[r_][1], mn[r_][2], mn[r_][3]);      \
            *(float4*)(p_ + (8 + r_) * 256) =                                 \
                make_float4(mx[r_][0], mx[r_][1], mx[r_][2], mx[r_][3]);      \
        }                                                                     \
    } while (0)

#define MERGE_STATE(slotbase)                                                 \
    do {                                                                      \
        const float* p_ = (slotbase) + lane * 4;                              \
        _Pragma("unroll")                                                     \
        for (int r_ = 0; r_ < 8; ++r_) {                                      \
            float4 vn_ = *(const float4*)(p_ + r_ * 256);                     \
            float4 vx_ = *(const float4*)(p_ + (8 + r_) * 256);               \
            mn[r_][0] = fminf(mn[r_][0], vn_.x);                              \
            mn[r_][1] = fminf(mn[r_][1], vn_.y);                              \
            mn[r_][2] = fminf(mn[r_][2], vn_.z);                              \
            mn[r_][3] = fminf(mn[r_][3], vn_.w);                              \
            mx[r_][0] = fmaxf(mx[r_][0], vx_.x);                              \
            mx[r_][1] = fmaxf(mx[r_][1], vx_.y);                              \
            mx[r_][2] = fmaxf(mx[r_][2], vx_.z);                              \
            mx[r_][3] = fmaxf(mx[r_][3], vx_.w);                              \
        }                                                                     \
    } while (0)

    float* slotA = lds;           // 4096 floats
    float* slotB = lds + 4096;

    __syncthreads();
    if (w == 2) DUMP_STATE(slotA);
    if (w == 3) DUMP_STATE(slotB);
    __syncthreads();
    if (w == 0) MERGE_STATE(slotA);   // w0 <- {w0,w2}
    if (w == 1) MERGE_STATE(slotB);   // w1 <- {w1,w3}
    __syncthreads();
    if (w == 1) DUMP_STATE(slotA);
    __syncthreads();
    if (w == 0) {
        MERGE_STATE(slotA);           // w0 <- all
        float* op = out + (size_t)(b0 + im * 8) * O_DIM + o0 + in_ * 4;
#pragma unroll
        for (int r = 0; r < 8; ++r)
            *(float4*)(op + (size_t)r * O_DIM) =
                make_float4(mn[r][0] + mx[r][0], mn[r][1] + mx[r][1],
                            mn[r][2] + mx[r][2], mn[r][3] + mx[r][3]);
    }
#undef DUMP_STATE
#undef MERGE_STATE
}

extern "C" void kernel_launch(void* const* d_in, const int* in_sizes, int n_in,
                              void* d_out, int out_size, void* d_ws, size_t ws_size,
                              hipStream_t stream) {
    (void)in_sizes; (void)n_in; (void)d_ws; (void)ws_size; (void)out_size;
    const float* X = (const float*)d_in[0];
    const float* W = (const float*)d_in[1];
    float* out     = (float*)d_out;

    dim3 grid(O_DIM / TN, B_DIM / TM);  // (32, 16) = 512 blocks = 2/CU
    tropical_gemm<<<grid, dim3(256), 0, stream>>>(X, W, out);
}